// Round 1
// 71.878 us; speedup vs baseline: 1.0119x; 1.0119x over previous
//
#include <hip/hip_runtime.h>

// 4-qubit quantum conv layer, closed-form simulation.
// Round-4: (a) q3 RX butterfly folded into the parity reduction via
//   pv0+pv1 = P0+P1            (norm preservation)
//   pv0-pv1 = cos(w3)(P0-P1) - 2 sin(w3) Im(a0 conj(a1))
// removing 64 FMA/thread; (b) explicit CSE of the phase partial sums
// (G/K/L each have only 4 distinct magnitudes; negation is a free src
// modifier on the consuming v_add).
//
// State index k: bit3=qubit0(b0), bit2=b1, bit1=b2, bit0=b3.
// Vector slot m (b1,b2,b3); lane .x = b0=0, .y = b0=1.
// CNOT ring folded into parity sign masks:
//   Z0' = par(b1,b2,b3), Z1' = par(b0,b1), Z2' = par(b0,b1,b2), Z3' = par(all).
// Output channels (B,4,14,14) = [Z3, Z2, Z1, Z0].

typedef float v2f __attribute__((ext_vector_type(2)));

#define NPATCH (4096 * 196)

__global__ __launch_bounds__(256) void qconv_kernel(
    const float* __restrict__ img,   // (4096,1,28,28)
    const float* __restrict__ w,     // (1,4)
    float* __restrict__ out)         // (4096,4,14,14)
{
    const int p = blockIdx.x * blockDim.x + threadIdx.x;   // grid == NPATCH exactly

    const int b   = p / 196;
    const int rem = p - b * 196;
    const int r   = rem / 14;
    const int c   = rem - r * 14;

    const float2* row0 = (const float2*)(img + b * 784 + (2 * r) * 28 + 2 * c);
    const float2* row1 = (const float2*)(img + b * 784 + (2 * r + 1) * 28 + 2 * c);
    const float2 p0 = row0[0];
    const float2 p1 = row1[0];
    const float x0 = p0.x, x1 = p0.y, x2 = p1.x, x3 = p1.y;

    // 0.785/2 * 1/(2pi): angle halves expressed in revolutions
    const float HRV = 0.785f * 0.5f * 0.15915494309189535f;
    const float t0 = x0 * HRV, t1 = x1 * HRV, t2 = x2 * HRV, t3 = x3 * HRV;
    const float u01 = x0 * x1 * HRV, u02 = x0 * x2 * HRV, u03 = x0 * x3 * HRV;
    const float u12 = x1 * x2 * HRV, u13 = x1 * x3 * HRV, u23 = x2 * x3 * HRV;

    // ---- phase construction with explicit shared partials ----
    // G(m) = s1*u01 + s2*u02 + s3*u03  (s=+1 iff bit set); G(m<4) = -G(7-m)
    const float A12p = u01 + u02, A12m = u01 - u02;
    const float G4 = A12m - u03, G5 = A12m + u03, G6 = A12p - u03, G7 = A12p + u03;
    // L(m) = s1*t1 + s2*t2 + s3*t3; L(m<4) = -L(7-m)
    const float B12p = t1 + t2, B12m = t1 - t2;
    const float L4 = B12m - t3, L5 = B12m + t3, L6 = B12p - t3, L7 = B12p + t3;
    // K(m) = sig12*u12 + sig13*u13 + sig23*u23 (sig=+1 iff XOR of the two bits);
    // K is complement-symmetric: K(m) = K(7-m)
    const float sa = u13 + u23, da = u13 - u23;
    const float K7 = -u12 - sa, K6 = sa - u12, K5 = u12 - da, K4 = u12 + da;
    // TK(m) = K(m) - t0 ; LG(m) = L(m)+G(m) for m>=4
    const float TK7 = K7 - t0, TK6 = K6 - t0, TK5 = K5 - t0, TK4 = K4 - t0;
    const float LG4 = L4 + G4, LG5 = L5 + G5, LG6 = L6 + G6, LG7 = L7 + G7;
    // E(m) = t0 - G(m)  (phi1 = phi0 + 2*E)
    const float E4 = t0 - G4, E5 = t0 - G5, E6 = t0 - G6, E7 = t0 - G7;
    const float E3 = t0 + G4, E2 = t0 + G5, E1 = t0 + G6, E0 = t0 + G7;

    float phi0[8], phi1[8];
    phi0[7] = TK7 + LG7;  phi0[0] = TK7 - LG7;
    phi0[6] = TK6 + LG6;  phi0[1] = TK6 - LG6;
    phi0[5] = TK5 + LG5;  phi0[2] = TK5 - LG5;
    phi0[4] = TK4 + LG4;  phi0[3] = TK4 - LG4;
    phi1[0] = fmaf(2.0f, E0, phi0[0]);
    phi1[1] = fmaf(2.0f, E1, phi0[1]);
    phi1[2] = fmaf(2.0f, E2, phi0[2]);
    phi1[3] = fmaf(2.0f, E3, phi0[3]);
    phi1[4] = fmaf(2.0f, E4, phi0[4]);
    phi1[5] = fmaf(2.0f, E5, phi0[5]);
    phi1[6] = fmaf(2.0f, E6, phi0[6]);
    phi1[7] = fmaf(2.0f, E7, phi0[7]);

    v2f srv[8], siv[8];
#pragma unroll
    for (int m = 0; m < 8; ++m) {
        srv[m].x = __builtin_amdgcn_cosf(phi0[m]);
        srv[m].y = __builtin_amdgcn_cosf(phi1[m]);
        siv[m].x = __builtin_amdgcn_sinf(phi0[m]);
        siv[m].y = __builtin_amdgcn_sinf(phi1[m]);
    }

    // ---- RX(w_q) layer; q0..q2 via butterflies, q3 folded into reduction ----
    const float RVF = 0.15915494309189535f;   // 1/(2pi)
    const float WRV = 0.5f * RVF;             // half-angle in revolutions
    const float w0 = w[0] * WRV, w1 = w[1] * WRV, w2 = w[2] * WRV;

    // qubit 0: butterfly across the vector lanes (.x <-> .y)
    {
        const float cq = __builtin_amdgcn_cosf(w0);
        const float sq = __builtin_amdgcn_sinf(w0);
#pragma unroll
        for (int m = 0; m < 8; ++m) {
            const float a0r = srv[m].x, a0i = siv[m].x;
            const float a1r = srv[m].y, a1i = siv[m].y;
            srv[m].x = cq * a0r + sq * a1i;
            siv[m].x = cq * a0i - sq * a1r;
            srv[m].y = cq * a1r + sq * a0i;
            siv[m].y = cq * a1i - sq * a0r;
        }
    }

    // qubits 1..2: packed butterflies within m-space (strides 4, 2)
#pragma unroll
    for (int q = 1; q < 3; ++q) {
        const float wq = (q == 1) ? w1 : w2;
        const float cq = __builtin_amdgcn_cosf(wq);
        const float sq = __builtin_amdgcn_sinf(wq);
        const int stride = 8 >> q;
#pragma unroll
        for (int m = 0; m < 8; ++m) {
            if (m & stride) continue;
            const int m1 = m | stride;
            const v2f A0r = srv[m], A0i = siv[m];
            const v2f A1r = srv[m1], A1i = siv[m1];
            srv[m]  = cq * A0r + sq * A1i;
            siv[m]  = cq * A0i - sq * A1r;
            srv[m1] = cq * A1r + sq * A0i;
            siv[m1] = cq * A1i - sq * A0r;
        }
    }

    // ---- q3 fold + parity reductions ----
    // For the q3 pair (b3=0,1):  pv0+pv1 = P0+P1
    //                            pv0-pv1 = cos(w3)(P0-P1) - 2 sin(w3) Im(a0 conj a1)
    const float cw3f = __builtin_amdgcn_cosf(w[3] * RVF);          // full angle
    const float s2w3 = 2.0f * __builtin_amdgcn_sinf(w[3] * RVF);

    v2f ta = {0.f, 0.f};  // sign = parity(b1)          -> e1
    v2f tb = {0.f, 0.f};  // sign = parity(b1^b2)       -> e2
    v2f tc = {0.f, 0.f};  // sign = parity(b1^b2^b3)    -> e0 / e3
#pragma unroll
    for (int mp = 0; mp < 8; mp += 2) {
        const int b1 = (mp >> 2) & 1, b2 = (mp >> 1) & 1;
        const v2f a0r = srv[mp],     a0i = siv[mp];
        const v2f a1r = srv[mp + 1], a1i = siv[mp + 1];
        const v2f P0 = a0r * a0r + a0i * a0i;
        const v2f P1 = a1r * a1r + a1i * a1i;
        const v2f X  = a0i * a1r - a0r * a1i;      // Im(a0 * conj(a1))
        const v2f S  = P0 + P1;
        const v2f D  = cw3f * (P0 - P1) - s2w3 * X;
        ta += (b1        ? -S : S);
        tb += ((b1 ^ b2) ? -S : S);
        tc += ((b1 ^ b2) ? -D : D);
    }
    const float SC = 0.0625f;  // (1/4 amplitude)^2 normalization
    const float e0 = (tc.x + tc.y) * SC;
    const float e1 = (ta.x - ta.y) * SC;
    const float e2 = (tb.x - tb.y) * SC;
    const float e3 = (tc.x - tc.y) * SC;

    // out[b, ch, r, c]; channels = [Z3, Z2, Z1, Z0]; rem == r*14+c
    float* o = out + b * 784 + rem;
    o[0 * 196] = e3;
    o[1 * 196] = e2;
    o[2 * 196] = e1;
    o[3 * 196] = e0;
}

extern "C" void kernel_launch(void* const* d_in, const int* in_sizes, int n_in,
                              void* d_out, int out_size, void* d_ws, size_t ws_size,
                              hipStream_t stream) {
    const float* img = (const float*)d_in[0];
    const float* w   = (const float*)d_in[1];
    float* out       = (float*)d_out;

    const int threads = 256;
    const int blocks  = NPATCH / threads;  // 3136, exact
    qconv_kernel<<<blocks, threads, 0, stream>>>(img, w, out);
}

// Round 3
// 70.822 us; speedup vs baseline: 1.0270x; 1.0149x over previous
//
#include <hip/hip_runtime.h>

// 4-qubit quantum conv layer, closed-form simulation.
// Round-6: round-5 structure with the phase sign conventions FIXED.
//   sigma_ij = +1 iff b_i^b_j = 1  ==>  sigma_ij = -s_i*s_j.
//   So U(n) = -(s0s1 u01 + s0s2 u02 + s1s2 u12)  (was +, wrong)
//   and the lane-odd part is s3*(t3 - V(n)), V(n)=s0 u03+s1 u13+s2 u23 (was t3+V).
// Structure: vector lane = qubit3 (b3); all three RX butterflies (q0,q1,q2)
// are pure v2f ops -> v_pk_fma_f32. q3 folded into the parity reduction.
// 2 adjacent patches per thread: shared float4 row loads, shared weight
// sin/cos, float2 coalesced stores.
//
// Slot n (b0,b1,b2) = (n>>2, (n>>1)&1, n&1); lane .x = b3=0, .y = b3=1.
// CNOT ring folded into parity sign masks:
//   Z0' = par(b1,b2,b3), Z1' = par(b0,b1), Z2' = par(b0,b1,b2), Z3' = par(all).
// Output channels (B,4,14,14) = [Z3, Z2, Z1, Z0].

typedef float v2f __attribute__((ext_vector_type(2)));

#define NPAIR (4096 * 98)   // 2 horizontally-adjacent patches per thread

__device__ __forceinline__ float4 qpatch(
    float x0, float x1, float x2, float x3,
    float cq0, float sq0, float cq1, float sq1, float cq2, float sq2,
    float cw3, float s2w3)
{
    // 0.785/2 * 1/(2pi): angle halves in revolutions
    const float HRV = 0.785f * 0.5f * 0.15915494309189535f;
    const float t0 = x0 * HRV, t1 = x1 * HRV, t2 = x2 * HRV, t3 = x3 * HRV;
    const float u01 = x0 * x1 * HRV, u02 = x0 * x2 * HRV, u03 = x0 * x3 * HRV;
    const float u12 = x1 * x2 * HRV, u13 = x1 * x3 * HRV, u23 = x2 * x3 * HRV;

    // phi(n,b3) = M(n) + s3*W(n);  M = T+U, W = t3-V   (s_q = +1 iff b_q=1)
    // T(n) = s0 t0 + s1 t1 + s2 t2            (T(n) = -T(7-n))
    const float a  = t0 - t1, bb = t0 + t1;
    const float T4 = a - t2,  T5 = a + t2,  T6 = bb - t2, T7 = bb + t2;
    // U(n) = -(s0s1 u01 + s0s2 u02 + s1s2 u12)   (U(n) = U(7-n))
    const float c  = u01 + u02, d = u01 - u02;
    const float U7 = -(c + u12), U6 = u12 - d, U5 = d + u12, U4 = c - u12;
    // V(n) = s0 u03 + s1 u13 + s2 u23          (V(n) = -V(7-n))
    const float e  = u03 - u13, f = u03 + u13;
    const float V4 = e - u23, V5 = e + u23, V6 = f - u23, V7 = f + u23;

    float Mp[8], W[8];
    Mp[7] = T7 + U7;  Mp[0] = U7 - T7;
    Mp[6] = T6 + U6;  Mp[1] = U6 - T6;
    Mp[5] = T5 + U5;  Mp[2] = U5 - T5;
    Mp[4] = T4 + U4;  Mp[3] = U4 - T4;
    W[7]  = t3 - V7;  W[0]  = t3 + V7;
    W[6]  = t3 - V6;  W[1]  = t3 + V6;
    W[5]  = t3 - V5;  W[2]  = t3 + V5;
    W[4]  = t3 - V4;  W[3]  = t3 + V4;

    v2f sr[8], si[8];
#pragma unroll
    for (int n = 0; n < 8; ++n) {
        const float p0 = Mp[n] - W[n];   // b3 = 0
        const float p1 = Mp[n] + W[n];   // b3 = 1
        sr[n].x = __builtin_amdgcn_cosf(p0);
        sr[n].y = __builtin_amdgcn_cosf(p1);
        si[n].x = __builtin_amdgcn_sinf(p0);
        si[n].y = __builtin_amdgcn_sinf(p1);
    }

    // RX butterflies on q0,q1,q2 (strides 4,2,1 over n) -- all packed v2f
#pragma unroll
    for (int q = 0; q < 3; ++q) {
        const float cq = (q == 0) ? cq0 : (q == 1) ? cq1 : cq2;
        const float sq = (q == 0) ? sq0 : (q == 1) ? sq1 : sq2;
        const int stride = 4 >> q;
#pragma unroll
        for (int n = 0; n < 8; ++n) {
            if (n & stride) continue;
            const int n1 = n | stride;
            const v2f A0r = sr[n],  A0i = si[n];
            const v2f A1r = sr[n1], A1i = si[n1];
            sr[n]  = cq * A0r + sq * A1i;
            si[n]  = cq * A0i - sq * A1r;
            sr[n1] = cq * A1r + sq * A0i;
            si[n1] = cq * A1i - sq * A0r;
        }
    }

    // q3 fold + parity reductions:
    //   p0+p1 = Px+Py ;  p0-p1 = cos(w3)(Px-Py) - 2 sin(w3) Im(ax conj(ay))
    float acc0 = 0.f, acc1 = 0.f, acc2 = 0.f, acc3 = 0.f;
#pragma unroll
    for (int n = 0; n < 8; ++n) {
        const int b0 = (n >> 2) & 1, b1 = (n >> 1) & 1, b2 = n & 1;
        const v2f P = sr[n] * sr[n] + si[n] * si[n];
        const float S  = P.x + P.y;
        const float X  = si[n].x * sr[n].y - sr[n].x * si[n].y;
        const float Dd = cw3 * (P.x - P.y) - s2w3 * X;
        acc1 += ((b0 ^ b1)      ? -S  : S);
        acc2 += ((b0 ^ b1 ^ b2) ? -S  : S);
        acc0 += ((b1 ^ b2)      ? -Dd : Dd);
        acc3 += ((b0 ^ b1 ^ b2) ? -Dd : Dd);
    }
    const float SC = 0.0625f;  // (1/4 amplitude)^2 normalization
    return make_float4(acc3 * SC, acc2 * SC, acc1 * SC, acc0 * SC);  // [Z3,Z2,Z1,Z0]
}

__global__ __launch_bounds__(256) void qconv_kernel(
    const float* __restrict__ img,   // (4096,1,28,28)
    const float* __restrict__ w,     // (1,4)
    float* __restrict__ out)         // (4096,4,14,14)
{
    const int p = blockIdx.x * blockDim.x + threadIdx.x;   // pair index, grid exact

    const int b   = p / 98;
    const int rem = p - b * 98;
    const int r   = rem / 7;
    const int k   = rem - r * 7;          // pair column; patches at c = 2k, 2k+1

    const float* base = img + b * 784 + r * 56 + k * 4;
    const float4 row0 = *(const float4*)(base);        // cols 4k..4k+3, row 2r
    const float4 row1 = *(const float4*)(base + 28);   // row 2r+1

    // weight trig (shared across both patches)
    const float RVF = 0.15915494309189535f;   // 1/(2pi)
    const float WRV = 0.5f * RVF;
    const float cq0 = __builtin_amdgcn_cosf(w[0] * WRV);
    const float sq0 = __builtin_amdgcn_sinf(w[0] * WRV);
    const float cq1 = __builtin_amdgcn_cosf(w[1] * WRV);
    const float sq1 = __builtin_amdgcn_sinf(w[1] * WRV);
    const float cq2 = __builtin_amdgcn_cosf(w[2] * WRV);
    const float sq2 = __builtin_amdgcn_sinf(w[2] * WRV);
    const float cw3  = __builtin_amdgcn_cosf(w[3] * RVF);
    const float s2w3 = 2.0f * __builtin_amdgcn_sinf(w[3] * RVF);

    const float4 ea = qpatch(row0.x, row0.y, row1.x, row1.y,
                             cq0, sq0, cq1, sq1, cq2, sq2, cw3, s2w3);
    const float4 eb = qpatch(row0.z, row0.w, row1.z, row1.w,
                             cq0, sq0, cq1, sq1, cq2, sq2, cw3, s2w3);

    // out[b, ch, r, c0..c0+1]; channels = [Z3, Z2, Z1, Z0]
    float* o = out + b * 784 + r * 14 + 2 * k;
    *(float2*)(o + 0 * 196) = make_float2(ea.x, eb.x);
    *(float2*)(o + 1 * 196) = make_float2(ea.y, eb.y);
    *(float2*)(o + 2 * 196) = make_float2(ea.z, eb.z);
    *(float2*)(o + 3 * 196) = make_float2(ea.w, eb.w);
}

extern "C" void kernel_launch(void* const* d_in, const int* in_sizes, int n_in,
                              void* d_out, int out_size, void* d_ws, size_t ws_size,
                              hipStream_t stream) {
    const float* img = (const float*)d_in[0];
    const float* w   = (const float*)d_in[1];
    float* out       = (float*)d_out;

    const int threads = 256;
    const int blocks  = NPAIR / threads;  // 1568, exact
    qconv_kernel<<<blocks, threads, 0, stream>>>(img, w, out);
}

// Round 4
// 69.023 us; speedup vs baseline: 1.0537x; 1.0261x over previous
//
#include <hip/hip_runtime.h>

// 4-qubit quantum conv layer, closed-form simulation.
// Round-7: lane axis repacked from b3 to (patchA, patchB). Every arithmetic
// op (phase construction, butterflies, q3-fold reduction) is now a packed
// v2f op processing both patches at once; only the 64 sin/cos remain scalar
// (v2f lanes are distinct VGPRs, so per-lane trans input is free).
// Output stores become direct v2f stores (lanes already = (patchA,patchB)).
//
// Verified sign conventions from round-6:
//   sigma_ij = -s_i*s_j ;  U(n) = -(s0s1 u01 + s0s2 u02 + s1s2 u12);
//   lane-odd part s3*(t3 - V(n)), V(n) = s0 u03 + s1 u13 + s2 u23.
// Slot j = (b0,b1,b2,b3) = (j>>3, (j>>2)&1, (j>>1)&1, j&1).
// Butterflies q0,q1,q2 = strides 8,4,2; q3 folded into parity reduction:
//   p0+p1 = P0+P1 ;  p0-p1 = cos(w3)(P0-P1) - 2 sin(w3) Im(a0 conj a1).
// CNOT ring folded into parity sign masks:
//   Z0' = par(b1,b2,b3), Z1' = par(b0,b1), Z2' = par(b0,b1,b2), Z3' = par(all).
// Output channels (B,4,14,14) = [Z3, Z2, Z1, Z0].

typedef float v2f __attribute__((ext_vector_type(2)));

#define NPAIR (4096 * 98)   // 2 horizontally-adjacent patches per thread

__global__ __launch_bounds__(256) void qconv_kernel(
    const float* __restrict__ img,   // (4096,1,28,28)
    const float* __restrict__ w,     // (1,4)
    float* __restrict__ out)         // (4096,4,14,14)
{
    const int p = blockIdx.x * blockDim.x + threadIdx.x;   // pair index, grid exact

    const int b   = p / 98;
    const int rem = p - b * 98;
    const int r   = rem / 7;
    const int k   = rem - r * 7;          // pair column; patches at c = 2k, 2k+1

    const float* base = img + b * 784 + r * 56 + k * 4;
    const float4 row0 = *(const float4*)(base);        // cols 4k..4k+3, row 2r
    const float4 row1 = *(const float4*)(base + 28);   // row 2r+1

    // lanes = (patchA, patchB)
    const v2f x0 = {row0.x, row0.z};
    const v2f x1 = {row0.y, row0.w};
    const v2f x2 = {row1.x, row1.z};
    const v2f x3 = {row1.y, row1.w};

    // 0.785/2 * 1/(2pi): angle halves in revolutions
    const float HRV = 0.785f * 0.5f * 0.15915494309189535f;
    const v2f t0 = x0 * HRV, t1 = x1 * HRV, t2 = x2 * HRV, t3 = x3 * HRV;
    const v2f u01 = x0 * x1 * HRV, u02 = x0 * x2 * HRV, u03 = x0 * x3 * HRV;
    const v2f u12 = x1 * x2 * HRV, u13 = x1 * x3 * HRV, u23 = x2 * x3 * HRV;

    // phi(n,b3) = M(n) + s3*W(n);  M = T+U, W = t3-V   (s_q = +1 iff b_q=1)
    // T(n) = s0 t0 + s1 t1 + s2 t2            (T(n) = -T(7-n))
    const v2f a  = t0 - t1, bb = t0 + t1;
    const v2f T4 = a - t2,  T5 = a + t2,  T6 = bb - t2, T7 = bb + t2;
    // U(n) = -(s0s1 u01 + s0s2 u02 + s1s2 u12)   (U(n) = U(7-n))
    const v2f c  = u01 + u02, d = u01 - u02;
    const v2f U7 = -(c + u12), U6 = u12 - d, U5 = d + u12, U4 = c - u12;
    // V(n) = s0 u03 + s1 u13 + s2 u23          (V(n) = -V(7-n))
    const v2f e  = u03 - u13, f = u03 + u13;
    const v2f V4 = e - u23, V5 = e + u23, V6 = f - u23, V7 = f + u23;

    v2f Mp[8], W[8];
    Mp[7] = T7 + U7;  Mp[0] = U7 - T7;
    Mp[6] = T6 + U6;  Mp[1] = U6 - T6;
    Mp[5] = T5 + U5;  Mp[2] = U5 - T5;
    Mp[4] = T4 + U4;  Mp[3] = U4 - T4;
    W[7]  = t3 - V7;  W[0]  = t3 + V7;
    W[6]  = t3 - V6;  W[1]  = t3 + V6;
    W[5]  = t3 - V5;  W[2]  = t3 + V5;
    W[4]  = t3 - V4;  W[3]  = t3 + V4;

    // state: slot j = 2n + b3, lanes = (patchA, patchB)
    v2f sr[16], si[16];
#pragma unroll
    for (int n = 0; n < 8; ++n) {
        const v2f ph0 = Mp[n] - W[n];   // b3 = 0
        const v2f ph1 = Mp[n] + W[n];   // b3 = 1
        sr[2 * n].x     = __builtin_amdgcn_cosf(ph0.x);
        sr[2 * n].y     = __builtin_amdgcn_cosf(ph0.y);
        si[2 * n].x     = __builtin_amdgcn_sinf(ph0.x);
        si[2 * n].y     = __builtin_amdgcn_sinf(ph0.y);
        sr[2 * n + 1].x = __builtin_amdgcn_cosf(ph1.x);
        sr[2 * n + 1].y = __builtin_amdgcn_cosf(ph1.y);
        si[2 * n + 1].x = __builtin_amdgcn_sinf(ph1.x);
        si[2 * n + 1].y = __builtin_amdgcn_sinf(ph1.y);
    }

    // weight trig (uniform)
    const float RVF = 0.15915494309189535f;   // 1/(2pi)
    const float WRV = 0.5f * RVF;
    const float cq0 = __builtin_amdgcn_cosf(w[0] * WRV);
    const float sq0 = __builtin_amdgcn_sinf(w[0] * WRV);
    const float cq1 = __builtin_amdgcn_cosf(w[1] * WRV);
    const float sq1 = __builtin_amdgcn_sinf(w[1] * WRV);
    const float cq2 = __builtin_amdgcn_cosf(w[2] * WRV);
    const float sq2 = __builtin_amdgcn_sinf(w[2] * WRV);
    const float cw3  = __builtin_amdgcn_cosf(w[3] * RVF);
    const float s2w3 = 2.0f * __builtin_amdgcn_sinf(w[3] * RVF);

    // RX butterflies on q0,q1,q2 (strides 8,4,2 over j) -- all packed v2f
#pragma unroll
    for (int q = 0; q < 3; ++q) {
        const float cq = (q == 0) ? cq0 : (q == 1) ? cq1 : cq2;
        const float sq = (q == 0) ? sq0 : (q == 1) ? sq1 : sq2;
        const int stride = 8 >> q;
#pragma unroll
        for (int j = 0; j < 16; ++j) {
            if (j & stride) continue;
            const int j1 = j | stride;
            const v2f A0r = sr[j],  A0i = si[j];
            const v2f A1r = sr[j1], A1i = si[j1];
            sr[j]  = cq * A0r + sq * A1i;
            si[j]  = cq * A0i - sq * A1r;
            sr[j1] = cq * A1r + sq * A0i;
            si[j1] = cq * A1i - sq * A0r;
        }
    }

    // q3 fold + parity reductions (all packed):
    //   p0+p1 = P0+P1 ;  p0-p1 = cos(w3)(P0-P1) - 2 sin(w3) Im(a0 conj a1)
    v2f acc0 = {0.f, 0.f}, acc1 = {0.f, 0.f}, acc2 = {0.f, 0.f}, acc3 = {0.f, 0.f};
#pragma unroll
    for (int n = 0; n < 8; ++n) {
        const int b0 = (n >> 2) & 1, b1 = (n >> 1) & 1, b2 = n & 1;
        const int j = 2 * n;
        const v2f P0 = sr[j] * sr[j] + si[j] * si[j];
        const v2f P1 = sr[j + 1] * sr[j + 1] + si[j + 1] * si[j + 1];
        const v2f S  = P0 + P1;
        const v2f X  = si[j] * sr[j + 1] - sr[j] * si[j + 1];  // Im(a0 conj a1)
        const v2f Dd = cw3 * (P0 - P1) - s2w3 * X;
        acc1 += ((b0 ^ b1)      ? -S  : S);
        acc2 += ((b0 ^ b1 ^ b2) ? -S  : S);
        acc0 += ((b1 ^ b2)      ? -Dd : Dd);
        acc3 += ((b0 ^ b1 ^ b2) ? -Dd : Dd);
    }
    const float SC = 0.0625f;  // (1/4 amplitude)^2 normalization

    // out[b, ch, r, 2k..2k+1]; channels = [Z3, Z2, Z1, Z0]; lanes already (A,B)
    float* o = out + b * 784 + r * 14 + 2 * k;
    *(v2f*)(o + 0 * 196) = acc3 * SC;
    *(v2f*)(o + 1 * 196) = acc2 * SC;
    *(v2f*)(o + 2 * 196) = acc1 * SC;
    *(v2f*)(o + 3 * 196) = acc0 * SC;
}

extern "C" void kernel_launch(void* const* d_in, const int* in_sizes, int n_in,
                              void* d_out, int out_size, void* d_ws, size_t ws_size,
                              hipStream_t stream) {
    const float* img = (const float*)d_in[0];
    const float* w   = (const float*)d_in[1];
    float* out       = (float*)d_out;

    const int threads = 256;
    const int blocks  = NPAIR / threads;  // 1568, exact
    qconv_kernel<<<blocks, threads, 0, stream>>>(img, w, out);
}